// Round 9
// baseline (160.753 us; speedup 1.0000x reference)
//
#include <hip/hip_runtime.h>
#include <stdint.h>

typedef float    f32x4 __attribute__((ext_vector_type(4)));
typedef short    s16x8 __attribute__((ext_vector_type(8)));
typedef short    s16x4 __attribute__((ext_vector_type(4)));
typedef unsigned short u16;
typedef uint32_t u32;

#define DEVINL __device__ __forceinline__

DEVINL float bf2f(u16 u) { union { u32 i; float f; } x; x.i = ((u32)u) << 16; return x.f; }
DEVINL u16 f2bf(float f) {
  union { float f; u32 i; } x; x.f = f;
  u32 i = x.i;
  return (u16)((i + 0x7FFFu + ((i >> 16) & 1u)) >> 16);  // RNE
}

DEVINL void gload16(const void* g, void* l) {
  __builtin_amdgcn_global_load_lds((const __attribute__((address_space(1))) void*)g,
                                   (__attribute__((address_space(3))) void*)l,
                                   16, 0, 0);
}

// --------------------------- prep: conv x->bf16 + both weight transposes
__global__ __launch_bounds__(256) void k_prep(const float* __restrict__ x,
                                              u16* __restrict__ xb,
                                              const float* __restrict__ Wqkv,
                                              u16* __restrict__ wqkvt,
                                              const float* __restrict__ Wout,
                                              u16* __restrict__ woutt) {
  __shared__ __align__(16) float t[64][65];
  int b = blockIdx.x;
  int tid = threadIdx.x;
  if (b < 2048) {
    const int n8 = 2097152;
    int stride = 2048 * 256;
    for (int i = b * 256 + tid; i < n8; i += stride) {
      const f32x4* p = (const f32x4*)(x + (size_t)i * 8);
      f32x4 a = p[0], c = p[1];
      s16x8 o;
      o[0] = (short)f2bf(a[0]); o[1] = (short)f2bf(a[1]);
      o[2] = (short)f2bf(a[2]); o[3] = (short)f2bf(a[3]);
      o[4] = (short)f2bf(c[0]); o[5] = (short)f2bf(c[1]);
      o[6] = (short)f2bf(c[2]); o[7] = (short)f2bf(c[3]);
      *(s16x8*)(xb + (size_t)i * 8) = o;
    }
    return;
  }
  const float* W; u16* Wt; int K, N, tb;
  if (b < 2048 + 192) { W = Wqkv; Wt = wqkvt; K = 512; N = 1536; tb = b - 2048; }
  else               { W = Wout; Wt = woutt; K = 512; N = 512;  tb = b - 2240; }
  int nb = N >> 6;
  int tn = tb % nb, tk = tb / nb;
  int n0 = tn << 6, k0 = tk << 6;
  int cr = tid >> 4, cc = (tid & 15) << 2;
#pragma unroll
  for (int i = 0; i < 4; i++) {
    int r = cr + (i << 4);
    f32x4 v = *(const f32x4*)(W + (size_t)(k0 + r) * N + n0 + cc);
    t[r][cc] = v[0]; t[r][cc + 1] = v[1]; t[r][cc + 2] = v[2]; t[r][cc + 3] = v[3];
  }
  __syncthreads();
#pragma unroll
  for (int i = 0; i < 4; i++) {
    int nn = cr + (i << 4);
    s16x4 o;
    o[0] = (short)f2bf(t[cc    ][nn]);
    o[1] = (short)f2bf(t[cc + 1][nn]);
    o[2] = (short)f2bf(t[cc + 2][nn]);
    o[3] = (short)f2bf(t[cc + 3][nn]);
    *(s16x4*)(Wt + (size_t)(n0 + nn) * K + k0 + cc) = o;
  }
}

// ------------------------------------------------------------------ GEMM1
// EXPERIMENT: 128x256 tile, 256 threads (4 waves 1Mx4N, wave tile 128x64),
// launch_bounds(256,2) -> TWO independent blocks/CU, with s_sleep(30)
// anti-phase stagger (~1920cy ~ half tile period) on the 2nd-resident-block
// candidates so one block's MFMA clusters overlap the other's LDS/stage
// phases. K-loop ledger identical to the proven r4 structure: BK=32, 3-deep
// LDS bufs (72 KiB), stage t+2 split across phases, counted vmcnt(6), never
// 0 until tail. Epilogue: q direct (+phi), k/v transposed 8B stores.
__global__ __launch_bounds__(256, 2) void k_g1(
    const u16* __restrict__ A, const u16* __restrict__ Bt,
    u16* __restrict__ qph, u16* __restrict__ kphT, u16* __restrict__ vT) {
  __shared__ __align__(16) u16 lsA[3][128 * 32];
  __shared__ __align__(16) u16 lsB[3][256 * 32];
  const int nbn = 6;
  int nwg = gridDim.x, bx = blockIdx.x;
  int o = (bx & 7) * (nwg >> 3) + (bx >> 3);   // XCD swizzle (1536%8==0)
  int bm = o / nbn, bn = o % nbn;
  int m0 = bm << 7, n0 = bn << 8;
  int tid = threadIdx.x, w = tid >> 6, lane = tid & 63;
  int lnlo = lane & 15, lnhi = lane >> 4;

  if ((bx >> 8) & 1) __builtin_amdgcn_s_sleep(30);   // anti-phase stagger

  const u16* gAp[2]; int lda[2];
#pragma unroll
  for (int i = 0; i < 2; i++) {
    int c = tid + i * 256, row = c >> 2, ch = c & 3;
    gAp[i] = A + (size_t)(m0 + row) * 512 + (ch ^ ((row >> 1) & 3)) * 8;
    lda[i] = c * 8;
  }
  const u16* gBp[4]; int ldb[4];
#pragma unroll
  for (int i = 0; i < 4; i++) {
    int c = tid + i * 256, row = c >> 2, ch = c & 3;
    gBp[i] = Bt + (size_t)(n0 + row) * 512 + (ch ^ ((row >> 1) & 3)) * 8;
    ldb[i] = c * 8;
  }
  int offA[8], offB[4];
#pragma unroll
  for (int f = 0; f < 8; f++) { int r = f * 16 + lnlo;          offA[f] = r * 32 + (lnhi ^ ((r >> 1) & 3)) * 8; }
#pragma unroll
  for (int f = 0; f < 4; f++) { int r = w * 64 + f * 16 + lnlo; offB[f] = r * 32 + (lnhi ^ ((r >> 1) & 3)) * 8; }

  f32x4 acc[8][4] = {};

#pragma unroll
  for (int tt = 0; tt < 2; tt++) {
#pragma unroll
    for (int i = 0; i < 2; i++) gload16(gAp[i] + tt * 32, &lsA[tt][lda[i]]);
#pragma unroll
    for (int i = 0; i < 4; i++) gload16(gBp[i] + tt * 32, &lsB[tt][ldb[i]]);
  }
  asm volatile("s_waitcnt vmcnt(6)" ::: "memory");   // tile 0 landed; 1 flying
  __builtin_amdgcn_s_barrier();

#pragma unroll
  for (int t = 0; t < 16; t++) {
    int buf = t % 3;
    const u16* La = &lsA[buf][0];
    const u16* Lb = &lsB[buf][0];
    int k2 = (t + 2) * 32, b2 = (t + 2) % 3;

    s16x8 bf[4], af[4];
#pragma unroll
    for (int f = 0; f < 4; f++) bf[f] = *(const s16x8*)(Lb + offB[f]);
#pragma unroll
    for (int f = 0; f < 4; f++) af[f] = *(const s16x8*)(La + offA[f]);
    if (t < 14) {
#pragma unroll
      for (int i = 0; i < 2; i++) gload16(gAp[i] + k2, &lsA[b2][lda[i]]);
    }
    __builtin_amdgcn_s_barrier();
    __builtin_amdgcn_s_setprio(1);
#pragma unroll
    for (int mf = 0; mf < 4; mf++)
#pragma unroll
      for (int nf = 0; nf < 4; nf++)
        acc[mf][nf] = __builtin_amdgcn_mfma_f32_16x16x32_bf16(af[mf], bf[nf], acc[mf][nf], 0, 0, 0);
    __builtin_amdgcn_s_setprio(0);
    __builtin_amdgcn_s_barrier();

    s16x8 af2[4];
#pragma unroll
    for (int f = 0; f < 4; f++) af2[f] = *(const s16x8*)(La + offA[4 + f]);
    if (t < 14) {
#pragma unroll
      for (int i = 0; i < 4; i++) gload16(gBp[i] + k2, &lsB[b2][ldb[i]]);
    }
    __builtin_amdgcn_s_barrier();
    __builtin_amdgcn_s_setprio(1);
#pragma unroll
    for (int mf = 0; mf < 4; mf++)
#pragma unroll
      for (int nf = 0; nf < 4; nf++)
        acc[4 + mf][nf] = __builtin_amdgcn_mfma_f32_16x16x32_bf16(af2[mf], bf[nf], acc[4 + mf][nf], 0, 0, 0);
    __builtin_amdgcn_s_setprio(0);
    if (t <= 13)      asm volatile("s_waitcnt vmcnt(6)" ::: "memory");  // t+1 landed
    else if (t == 14) asm volatile("s_waitcnt vmcnt(0)" ::: "memory");
    if (t < 15) __builtin_amdgcn_s_barrier();
  }

  int gnB = n0 + w * 64;
  int sec = n0 >> 9;                       // block-uniform (256-col tile)
  if (sec == 0) {
#pragma unroll
    for (int mf = 0; mf < 8; mf++) {
#pragma unroll
      for (int nf = 0; nf < 4; nf++) {
        int col = gnB + nf * 16 + lnlo;
        int hh = (col >> 6) & 7;
        int dd = col & 63;
#pragma unroll
        for (int r = 0; r < 4; r++) {
          int rowm = m0 + mf * 16 + lnhi * 4 + r;
          float val = acc[mf][nf][r];
          val = (val > 0.f) ? (val + 1.f) : __expf(val);  // elu+1
          int bidx = rowm >> 12, tok = rowm & 4095;
          qph[(((size_t)(bidx * 8 + hh) * 4096 + tok) << 6) + dd] = f2bf(val);
        }
      }
    }
  } else {
    u16* dstT = (sec == 1) ? kphT : vT;    // [bh][d=64][n=4096]
    bool isphi = (sec == 1);
#pragma unroll
    for (int mf = 0; mf < 8; mf++) {
      int rowm = m0 + mf * 16 + lnhi * 4;
      int bidx = rowm >> 12, tok = rowm & 4095;
#pragma unroll
      for (int nf = 0; nf < 4; nf++) {
        int col = gnB + nf * 16 + lnlo;
        int hh = (col >> 6) & 7;
        int dd = col & 63;
        s16x4 o4;
#pragma unroll
        for (int r = 0; r < 4; r++) {
          float val = acc[mf][nf][r];
          if (isphi) val = (val > 0.f) ? (val + 1.f) : __expf(val);
          o4[r] = (short)f2bf(val);
        }
        *(s16x4*)&dstT[((size_t)(bidx * 8 + hh) * 64 + dd) * 4096 + tok] = o4;
      }
    }
  }
}

// ------------------------------------------------------------------- GEMM2
// r4 structure verbatim (512 thr, 256x256, BK=32, 3-deep, counted vmcnt).
template <int EPI>
__global__ __launch_bounds__(512, 1) void k_gemm(
    const u16* __restrict__ A, const u16* __restrict__ Bt,
    int nbn,
    u16* __restrict__ qph, u16* __restrict__ kphT, u16* __restrict__ vT,
    float* __restrict__ out, const float* __restrict__ bias) {
  __shared__ __align__(16) u16 lsA[3][256 * 32];
  __shared__ __align__(16) u16 lsB[3][256 * 32];

  int nwg = gridDim.x;
  int bx = blockIdx.x;
  int o = (bx & 7) * (nwg >> 3) + (bx >> 3);
  int bm = o / nbn, bn = o % nbn;
  int m0 = bm << 8, n0 = bn << 8;
  int tid = threadIdx.x;
  int w = tid >> 6, lane = tid & 63;
  int lnlo = lane & 15, lnhi = lane >> 4;
  int wr = w >> 2, wc = w & 3;

  const u16* gAp[2]; const u16* gBp[2]; int ldst[2];
#pragma unroll
  for (int i = 0; i < 2; i++) {
    int c = tid + i * 512;
    int row = c >> 2, ch = c & 3;
    int gch = ch ^ ((row >> 1) & 3);
    gAp[i] = A + (size_t)(m0 + row) * 512 + gch * 8;
    gBp[i] = Bt + (size_t)(n0 + row) * 512 + gch * 8;
    ldst[i] = c * 8;
  }

  int offA[8], offB[4];
#pragma unroll
  for (int f = 0; f < 8; f++) {
    int r = wr * 128 + f * 16 + lnlo;
    offA[f] = r * 32 + (lnhi ^ ((r >> 1) & 3)) * 8;
  }
#pragma unroll
  for (int f = 0; f < 4; f++) {
    int r = wc * 64 + f * 16 + lnlo;
    offB[f] = r * 32 + (lnhi ^ ((r >> 1) & 3)) * 8;
  }

  f32x4 acc[8][4] = {};

#pragma unroll
  for (int i = 0; i < 2; i++) gload16(gAp[i], &lsA[0][ldst[i]]);
#pragma unroll
  for (int i = 0; i < 2; i++) gload16(gBp[i], &lsB[0][ldst[i]]);
#pragma unroll
  for (int i = 0; i < 2; i++) gload16(gAp[i] + 32, &lsA[1][ldst[i]]);
#pragma unroll
  for (int i = 0; i < 2; i++) gload16(gBp[i] + 32, &lsB[1][ldst[i]]);
  asm volatile("s_waitcnt vmcnt(4)" ::: "memory");
  __builtin_amdgcn_s_barrier();

#pragma unroll
  for (int t = 0; t < 16; t++) {
    int buf = t % 3;
    const u16* La = &lsA[buf][0];
    const u16* Lb = &lsB[buf][0];
    int k2 = (t + 2) * 32;
    int b2 = (t + 2) % 3;

    s16x8 bf[4], af[4];
#pragma unroll
    for (int f = 0; f < 4; f++) bf[f] = *(const s16x8*)(Lb + offB[f]);
#pragma unroll
    for (int f = 0; f < 4; f++) af[f] = *(const s16x8*)(La + offA[f]);
    if (t < 14) {
#pragma unroll
      for (int i = 0; i < 2; i++) gload16(gAp[i] + k2, &lsA[b2][ldst[i]]);
    }
    __builtin_amdgcn_s_barrier();
    __builtin_amdgcn_s_setprio(1);
#pragma unroll
    for (int mf = 0; mf < 4; mf++)
#pragma unroll
      for (int nf = 0; nf < 4; nf++)
        acc[mf][nf] = __builtin_amdgcn_mfma_f32_16x16x32_bf16(af[mf], bf[nf], acc[mf][nf], 0, 0, 0);
    __builtin_amdgcn_s_setprio(0);
    __builtin_amdgcn_s_barrier();

    s16x8 af2[4];
#pragma unroll
    for (int f = 0; f < 4; f++) af2[f] = *(const s16x8*)(La + offA[4 + f]);
    if (t < 14) {
#pragma unroll
      for (int i = 0; i < 2; i++) gload16(gBp[i] + k2, &lsB[b2][ldst[i]]);
    }
    __builtin_amdgcn_s_barrier();
    __builtin_amdgcn_s_setprio(1);
#pragma unroll
    for (int mf = 0; mf < 4; mf++)
#pragma unroll
      for (int nf = 0; nf < 4; nf++)
        acc[4 + mf][nf] = __builtin_amdgcn_mfma_f32_16x16x32_bf16(af2[mf], bf[nf], acc[4 + mf][nf], 0, 0, 0);
    __builtin_amdgcn_s_setprio(0);
    if (t <= 13)      asm volatile("s_waitcnt vmcnt(4)" ::: "memory");
    else if (t == 14) asm volatile("s_waitcnt vmcnt(0)" ::: "memory");
    if (t < 15) __builtin_amdgcn_s_barrier();
  }

  int gmB = m0 + wr * 128;
  int gnB = n0 + wc * 64;
#pragma unroll
  for (int mf = 0; mf < 8; mf++) {
#pragma unroll
    for (int nf = 0; nf < 4; nf++) {
      int col = gnB + nf * 16 + lnlo;
      float bv = bias[col];
#pragma unroll
      for (int r = 0; r < 4; r++) {
        int rowm = gmB + mf * 16 + lnhi * 4 + r;
        out[(size_t)rowm * 512 + col] = acc[mf][nf][r] + bv;
      }
    }
  }
}

// -------------------------------------------- KV partials via MFMA + Ksum
__global__ __launch_bounds__(256, 2) void k_kv(const u16* __restrict__ kphT,
                                               const u16* __restrict__ vT,
                                               float* __restrict__ kvpart,
                                               float* __restrict__ kspart) {
  __shared__ __align__(16) u16 lsK[64 * 256];   // 32 KB
  __shared__ __align__(16) u16 lsV[64 * 256];   // 32 KB
  __shared__ float red[4][64];
  int bx = blockIdx.x;
  int bh = bx >> 4, ck = bx & 15;
  int tid = threadIdx.x, w = tid >> 6, lane = tid & 63;
  int lnlo = lane & 15, lnhi = lane >> 4;
  size_t gbase = (size_t)bh * 64 * 4096 + ck * 256;

#pragma unroll
  for (int i = 0; i < 8; i++) {
    int c = tid + i * 256;
    int row = c >> 5, ch = c & 31;
    int gch = ch ^ (row & 31);
    gload16(kphT + gbase + (size_t)row * 4096 + gch * 8, &lsK[c * 8]);
  }
#pragma unroll
  for (int i = 0; i < 8; i++) {
    int c = tid + i * 256;
    int row = c >> 5, ch = c & 31;
    int gch = ch ^ (row & 31);
    gload16(vT + gbase + (size_t)row * 4096 + gch * 8, &lsV[c * 8]);
  }
  asm volatile("s_waitcnt vmcnt(0)" ::: "memory");
  __builtin_amdgcn_s_barrier();

  f32x4 acc[4] = {{0.f, 0.f, 0.f, 0.f}, {0.f, 0.f, 0.f, 0.f},
                  {0.f, 0.f, 0.f, 0.f}, {0.f, 0.f, 0.f, 0.f}};
  int rb = w * 16 + lnlo;
#pragma unroll
  for (int kk = 0; kk < 8; kk++) {
    s16x8 bfr = *(const s16x8*)&lsV[rb * 256 + ((kk * 4 + lnhi) ^ (rb & 31)) * 8];
#pragma unroll
    for (int mf = 0; mf < 4; mf++) {
      int ra = mf * 16 + lnlo;
      s16x8 af = *(const s16x8*)&lsK[ra * 256 + ((kk * 4 + lnhi) ^ (ra & 31)) * 8];
      acc[mf] = __builtin_amdgcn_mfma_f32_16x16x32_bf16(af, bfr, acc[mf], 0, 0, 0);
    }
  }

  {
    int d = tid & 63, q = tid >> 6;
    float s = 0.f;
#pragma unroll
    for (int j = 0; j < 8; j++) {
      s16x8 v8 = *(const s16x8*)&lsK[d * 256 + (q * 8 + j) * 8];
#pragma unroll
      for (int e = 0; e < 8; e++) s += bf2f((u16)v8[e]);
    }
    red[q][d] = s;
  }
  __syncthreads();

  size_t pb = (size_t)(bh * 16 + ck) * 4096;
#pragma unroll
  for (int mf = 0; mf < 4; mf++)
#pragma unroll
    for (int r = 0; r < 4; r++)
      kvpart[pb + (size_t)(mf * 16 + lnhi * 4 + r) * 64 + (w * 16 + lnlo)] = acc[mf][r];
  if (tid < 64)
    kspart[(size_t)(bh * 16 + ck) * 64 + tid] =
        red[0][tid] + red[1][tid] + red[2][tid] + red[3][tid];
}

// --------------------- reduce partials -> KVt[e][d] bf16 (pre-swizzled) + Ksum
__global__ __launch_bounds__(256) void k_kvred(const float* __restrict__ kvpart,
                                               const float* __restrict__ kspart,
                                               u16* __restrict__ kvt_sw,
                                               float* __restrict__ ksum) {
  int bh = blockIdx.x;
  int tid = threadIdx.x;
  int e = tid >> 2, d0 = (tid & 3) * 16;
  size_t pb = (size_t)bh * 16 * 4096;
#pragma unroll
  for (int dd = 0; dd < 16; dd++) {
    int d = d0 + dd;
    float s = 0.f;
#pragma unroll
    for (int c = 0; c < 16; c++) s += kvpart[pb + (size_t)c * 4096 + d * 64 + e];
    int chs = (d >> 3) ^ (e & 7);
    kvt_sw[((size_t)bh * 64 + e) * 64 + chs * 8 + (d & 7)] = f2bf(s);
  }
  if (tid < 64) {
    float s = 0.f;
#pragma unroll
    for (int c = 0; c < 16; c++) s += kspart[(size_t)bh * 1024 + c * 64 + tid];
    ksum[bh * 64 + tid] = s;
  }
}

// ------------------------- y[tok][h*64+e] = (q_phi @ KV) / (q_phi . Ksum + eps)
__global__ __launch_bounds__(256, 2) void k_attnout(const u16* __restrict__ qphi,
                                                    const u16* __restrict__ kvt_sw,
                                                    const float* __restrict__ ksum,
                                                    u16* __restrict__ y) {
  __shared__ __align__(16) u16 qa[256 * 64];
  __shared__ __align__(16) u16 bb[64 * 64];
  __shared__ float ksl[64];
  __shared__ float rdnl[256];
  int bx = blockIdx.x;
  int bh = bx >> 4, tch = bx & 15;
  int b = bh >> 3, hh = bh & 7;
  int tid = threadIdx.x, w = tid >> 6, lane = tid & 63;
  int lnlo = lane & 15, lnhi = lane >> 4;
  size_t qbase = ((size_t)bh * 4096 + tch * 256) * 64;

#pragma unroll
  for (int i = 0; i < 8; i++) {
    int c = i * 256 + tid;
    int row = c >> 3, ch = c & 7;
    int gcol = (ch ^ (row & 7)) << 3;
    gload16(qphi + qbase + (size_t)row * 64 + gcol, &qa[c * 8]);
  }
#pragma unroll
  for (int i = 0; i < 2; i++) {
    int c = i * 256 + tid;
    gload16(kvt_sw + (size_t)bh * 4096 + c * 8, &bb[c * 8]);
  }
  if (tid < 64) ksl[tid] = ksum[bh * 64 + tid];
  __syncthreads();

  {
    float den = 0.f;
#pragma unroll
    for (int ch = 0; ch < 8; ch++) {
      s16x8 v8 = *(const s16x8*)&qa[tid * 64 + ((ch ^ (tid & 7)) << 3)];
#pragma unroll
      for (int j = 0; j < 8; j++) den += bf2f((u16)v8[j]) * ksl[ch * 8 + j];
    }
    rdnl[tid] = 1.f / (den + 1e-6f);
  }
  __syncthreads();

  f32x4 acc[4][4] = {};
#pragma unroll
  for (int kk = 0; kk < 2; kk++) {
    s16x8 af[4], bfr[4];
#pragma unroll
    for (int f = 0; f < 4; f++) {
      int ra = w * 64 + f * 16 + lnlo;
      int ca = (kk * 4 + lnhi) ^ (ra & 7);
      af[f] = *(const s16x8*)&qa[ra * 64 + ca * 8];
      int rb = f * 16 + lnlo;
      int cb = (kk * 4 + lnhi) ^ (rb & 7);
      bfr[f] = *(const s16x8*)&bb[rb * 64 + cb * 8];
    }
#pragma unroll
    for (int mf = 0; mf < 4; mf++)
#pragma unroll
      for (int nf = 0; nf < 4; nf++)
        acc[mf][nf] = __builtin_amdgcn_mfma_f32_16x16x32_bf16(af[mf], bfr[nf], acc[mf][nf], 0, 0, 0);
  }

  size_t yrow0 = (size_t)b * 4096 + tch * 256;
#pragma unroll
  for (int mf = 0; mf < 4; mf++) {
#pragma unroll
    for (int nf = 0; nf < 4; nf++) {
      int e = nf * 16 + lnlo;
#pragma unroll
      for (int r = 0; r < 4; r++) {
        int tl = w * 64 + mf * 16 + lnhi * 4 + r;
        float val = acc[mf][nf][r] * rdnl[tl];
        y[(yrow0 + tl) * 512 + hh * 64 + e] = f2bf(val);
      }
    }
  }
}

// ------------------------------------------------------------------ launch
#define OFF_XB     ((size_t)0)             // 33,554,432  (also aliased as Y)
#define OFF_WQKVT  ((size_t)33554432)      //  1,572,864
#define OFF_WOUTT  ((size_t)35127296)      //    524,288
#define OFF_QPHI   ((size_t)35651584)      // 33,554,432
#define OFF_KPHI   ((size_t)69206016)      // 33,554,432  (kphiT [bh][64][4096])
#define OFF_VBUF   ((size_t)102760448)     // 33,554,432  (vT    [bh][64][4096])
#define OFF_KVPART ((size_t)136314880)     // 16,777,216
#define OFF_KSPART ((size_t)153092096)     //    262,144
#define OFF_KVT    ((size_t)153354240)     //    524,288
#define OFF_KSUM   ((size_t)153878528)     //     16,384

extern "C" void kernel_launch(void* const* d_in, const int* in_sizes, int n_in,
                              void* d_out, int out_size, void* d_ws, size_t ws_size,
                              hipStream_t stream) {
  const float* x    = (const float*)d_in[0];
  const float* Wqkv = (const float*)d_in[1];
  const float* Wout = (const float*)d_in[2];
  const float* bout = (const float*)d_in[3];
  float* out = (float*)d_out;
  char* ws = (char*)d_ws;

  u16* xb     = (u16*)(ws + OFF_XB);
  u16* y      = (u16*)(ws + OFF_XB);  // alias: xb dead after GEMM1
  u16* wqkvt  = (u16*)(ws + OFF_WQKVT);
  u16* woutt  = (u16*)(ws + OFF_WOUTT);
  u16* qphi   = (u16*)(ws + OFF_QPHI);
  u16* kphT   = (u16*)(ws + OFF_KPHI);
  u16* vT     = (u16*)(ws + OFF_VBUF);
  float* kvpart = (float*)(ws + OFF_KVPART);
  float* kspart = (float*)(ws + OFF_KSPART);
  u16* kvt_sw = (u16*)(ws + OFF_KVT);
  float* ksum = (float*)(ws + OFF_KSUM);

  k_prep<<<2304, 256, 0, stream>>>(x, xb, Wqkv, wqkvt, Wout, woutt);

  // qkv = xb @ Wqkv. 128-row x 256-col tiles: 256x6 = 1536 blocks, 2/CU.
  k_g1<<<1536, 256, 0, stream>>>(xb, wqkvt, qphi, kphT, vT);
  k_kv<<<64 * 16, 256, 0, stream>>>(kphT, vT, kvpart, kspart);
  k_kvred<<<64, 256, 0, stream>>>(kvpart, kspart, kvt_sw, ksum);
  k_attnout<<<64 * 16, 256, 0, stream>>>(qphi, kvt_sw, ksum, y);
  // out = y @ Wout + b. 128x2 = 256 blocks
  k_gemm<1><<<256, 512, 0, stream>>>(y, woutt, 2, nullptr, nullptr, nullptr, out, bout);
}

// Round 10
// 155.711 us; speedup vs baseline: 1.0324x; 1.0324x over previous
//
#include <hip/hip_runtime.h>
#include <stdint.h>

typedef float    f32x4 __attribute__((ext_vector_type(4)));
typedef short    s16x8 __attribute__((ext_vector_type(8)));
typedef short    s16x4 __attribute__((ext_vector_type(4)));
typedef unsigned short u16;
typedef uint32_t u32;

#define DEVINL __device__ __forceinline__
#define BARF do { asm volatile("" ::: "memory"); __builtin_amdgcn_s_barrier(); asm volatile("" ::: "memory"); } while (0)

DEVINL float bf2f(u16 u) { union { u32 i; float f; } x; x.i = ((u32)u) << 16; return x.f; }
DEVINL u16 f2bf(float f) {
  union { float f; u32 i; } x; x.f = f;
  u32 i = x.i;
  return (u16)((i + 0x7FFFu + ((i >> 16) & 1u)) >> 16);  // RNE
}

DEVINL void gload16(const void* g, void* l) {
  __builtin_amdgcn_global_load_lds((const __attribute__((address_space(1))) void*)g,
                                   (__attribute__((address_space(3))) void*)l,
                                   16, 0, 0);
}

// --------------------------- prep: conv x->bf16 + both weight transposes
__global__ __launch_bounds__(256) void k_prep(const float* __restrict__ x,
                                              u16* __restrict__ xb,
                                              const float* __restrict__ Wqkv,
                                              u16* __restrict__ wqkvt,
                                              const float* __restrict__ Wout,
                                              u16* __restrict__ woutt) {
  __shared__ __align__(16) float t[64][65];
  int b = blockIdx.x;
  int tid = threadIdx.x;
  if (b < 2048) {
    const int n8 = 2097152;
    int stride = 2048 * 256;
    for (int i = b * 256 + tid; i < n8; i += stride) {
      const f32x4* p = (const f32x4*)(x + (size_t)i * 8);
      f32x4 a = p[0], c = p[1];
      s16x8 o;
      o[0] = (short)f2bf(a[0]); o[1] = (short)f2bf(a[1]);
      o[2] = (short)f2bf(a[2]); o[3] = (short)f2bf(a[3]);
      o[4] = (short)f2bf(c[0]); o[5] = (short)f2bf(c[1]);
      o[6] = (short)f2bf(c[2]); o[7] = (short)f2bf(c[3]);
      *(s16x8*)(xb + (size_t)i * 8) = o;
    }
    return;
  }
  const float* W; u16* Wt; int K, N, tb;
  if (b < 2048 + 192) { W = Wqkv; Wt = wqkvt; K = 512; N = 1536; tb = b - 2048; }
  else               { W = Wout; Wt = woutt; K = 512; N = 512;  tb = b - 2240; }
  int nb = N >> 6;
  int tn = tb % nb, tk = tb / nb;
  int n0 = tn << 6, k0 = tk << 6;
  int cr = tid >> 4, cc = (tid & 15) << 2;
#pragma unroll
  for (int i = 0; i < 4; i++) {
    int r = cr + (i << 4);
    f32x4 v = *(const f32x4*)(W + (size_t)(k0 + r) * N + n0 + cc);
    t[r][cc] = v[0]; t[r][cc + 1] = v[1]; t[r][cc + 2] = v[2]; t[r][cc + 3] = v[3];
  }
  __syncthreads();
#pragma unroll
  for (int i = 0; i < 4; i++) {
    int nn = cr + (i << 4);
    s16x4 o;
    o[0] = (short)f2bf(t[cc    ][nn]);
    o[1] = (short)f2bf(t[cc + 1][nn]);
    o[2] = (short)f2bf(t[cc + 2][nn]);
    o[3] = (short)f2bf(t[cc + 3][nn]);
    *(s16x4*)(Wt + (size_t)(n0 + nn) * K + k0 + cc) = o;
  }
}

// ------------------------------------------------------------------- GEMM
// Faithful m201 8-phase template, K=512. 256x256 tile, 512 thr (8 waves
// 2Mx4N, wave tile 128x64), BK=64, 2 K-tiles/iter, 4 iters. LDS 128 KiB:
// [2 dbuf][2 half][128x64] for A and B. Per phase: {4-8 ds_read_b128 |
// 1 half-tile stage (2 gload16)} -> barrier -> setprio + 16 MFMA -> barrier.
// Counted vmcnt(2) ONLY at phases 4 and 8 (tail: vmcnt(0) once).
// Race ledger (verified): stage targets a half whose last read finished at a
// preceding phase-end barrier; stage slots: ph1-3 -> buf1 {B1,A0,A1} of tile
// 2j+1; ph4-7 -> buf0 {B0,B1,A0,A1} of 2j+2; ph8 -> buf1 B0 of 2j+3.
// ph4-end vmcnt(2): outstanding {tb.B0,B1,A0,A1, tn.B0}=10 -> 8 oldest (all
// of tile 2j+1) landed. ph8-end vmcnt(2): same for tile 2j+2. Per-wave vmcnt
// + barrier join => all waves' stages landed. Swizzle ch^(r&7) both sides.
template <int EPI>
__global__ __launch_bounds__(512, 1) void k_gemm(
    const u16* __restrict__ A, const u16* __restrict__ Bt, int nbn,
    u16* __restrict__ qph, u16* __restrict__ kphT, u16* __restrict__ vT,
    float* __restrict__ out, const float* __restrict__ bias) {
  __shared__ __align__(16) u16 lsA[2][2][128 * 64];
  __shared__ __align__(16) u16 lsB[2][2][128 * 64];

  int nwg = gridDim.x, bx = blockIdx.x;
  int o = (bx & 7) * (nwg >> 3) + (bx >> 3);     // XCD swizzle (nwg%8==0)
  int bm = o / nbn, bn = o % nbn;
  int m0 = bm << 8, n0 = bn << 8;
  int tid = threadIdx.x, w = tid >> 6, lane = tid & 63;
  int lnlo = lane & 15, lnhi = lane >> 4;
  int wr = w >> 2, wc = w & 3;

  // staging: half-tile = 128 rows x 8 chunks(16B) = 1024 chunks; thread owns
  // chunks tid, tid+512. LDS dest linear; global col pre-swizzled ch^(r&7).
  int c0 = tid, c1 = tid + 512;
  int r0 = c0 >> 3, r1 = c1 >> 3;
  int g0 = ((c0 & 7) ^ (r0 & 7)) * 8, g1 = ((c1 & 7) ^ (r1 & 7)) * 8;
  const u16* gA[2][2]; const u16* gB[2][2];
#pragma unroll
  for (int h = 0; h < 2; h++) {
    gA[h][0] = A + (size_t)(m0 + h * 128 + r0) * 512 + g0;
    gA[h][1] = A + (size_t)(m0 + h * 128 + r1) * 512 + g1;
    gB[h][0] = Bt + (size_t)(n0 + h * 128 + r0) * 512 + g0;
    gB[h][1] = Bt + (size_t)(n0 + h * 128 + r1) * 512 + g1;
  }
  int l0 = c0 * 8, l1 = c1 * 8;

  auto SA = [&](int buf, int h, int kt) {
    gload16(gA[h][0] + kt * 64, &lsA[buf][h][l0]);
    gload16(gA[h][1] + kt * 64, &lsA[buf][h][l1]);
  };
  auto SB = [&](int buf, int h, int kt) {
    gload16(gB[h][0] + kt * 64, &lsB[buf][h][l0]);
    gload16(gB[h][1] + kt * 64, &lsB[buf][h][l1]);
  };

  // fragment LDS offsets (u16), within wave's half; swizzled read side
  int offA[2][8], offB[2][4];
#pragma unroll
  for (int kk = 0; kk < 2; kk++) {
#pragma unroll
    for (int mf = 0; mf < 8; mf++) {
      int r = mf * 16 + lnlo;
      offA[kk][mf] = r * 64 + (((kk * 4 + lnhi) ^ (r & 7))) * 8;
    }
#pragma unroll
    for (int nf = 0; nf < 4; nf++) {
      int r = (wc & 1) * 64 + nf * 16 + lnlo;
      offB[kk][nf] = r * 64 + (((kk * 4 + lnhi) ^ (r & 7))) * 8;
    }
  }
  const u16* LA0 = &lsA[0][wr][0];
  const u16* LA1 = &lsA[1][wr][0];
  const u16* LB0 = &lsB[0][wc >> 1][0];
  const u16* LB1 = &lsB[1][wc >> 1][0];

  f32x4 acc[8][4] = {};
  s16x8 af[4], bf[4];

  auto rdA = [&](const u16* base, int kk, int g) {
#pragma unroll
    for (int f = 0; f < 4; f++) af[f] = *(const s16x8*)(base + offA[kk][g * 4 + f]);
  };
  auto rdB = [&](const u16* base, int kk) {
#pragma unroll
    for (int f = 0; f < 4; f++) bf[f] = *(const s16x8*)(base + offB[kk][f]);
  };
  auto MG = [&](int g) {
    __builtin_amdgcn_s_setprio(1);
#pragma unroll
    for (int mf = 0; mf < 4; mf++)
#pragma unroll
      for (int nf = 0; nf < 4; nf++)
        acc[g * 4 + mf][nf] =
            __builtin_amdgcn_mfma_f32_16x16x32_bf16(af[mf], bf[nf], acc[g * 4 + mf][nf], 0, 0, 0);
    __builtin_amdgcn_s_setprio(0);
  };

  // prologue: T0 -> buf0 fully; T1.B0 -> buf1
  SB(0, 0, 0); SB(0, 1, 0); SA(0, 0, 0); SA(0, 1, 0); SB(1, 0, 1);
  asm volatile("s_waitcnt vmcnt(2)" ::: "memory");   // T0 landed; T1.B0 flying
  BARF;

#pragma unroll
  for (int j = 0; j < 4; j++) {
    const int tb = 2 * j + 1, tn0 = 2 * j + 2, tn1 = 2 * j + 3;
    const bool st = (j < 3);
    // ---- ph1: buf0 kk0 g0 | stage b1.B1(tb)
    rdB(LB0, 0); rdA(LA0, 0, 0); SB(1, 1, tb);
    BARF; MG(0); BARF;
    // ---- ph2: buf0 kk0 g1 | stage b1.A0(tb)
    rdA(LA0, 0, 1); SA(1, 0, tb);
    BARF; MG(1); BARF;
    // ---- ph3: buf0 kk1 g0 | stage b1.A1(tb)
    rdB(LB0, 1); rdA(LA0, 1, 0); SA(1, 1, tb);
    BARF; MG(0); BARF;
    // ---- ph4: buf0 kk1 g1 | stage b0.B0(tn0) | vmcnt
    rdA(LA0, 1, 1);
    if (st) SB(0, 0, tn0);
    BARF; MG(1);
    if (st) asm volatile("s_waitcnt vmcnt(2)" ::: "memory");
    else    asm volatile("s_waitcnt vmcnt(0)" ::: "memory");
    BARF;
    // ---- ph5: buf1 kk0 g0 | stage b0.B1(tn0)
    rdB(LB1, 0); rdA(LA1, 0, 0);
    if (st) SB(0, 1, tn0);
    BARF; MG(0); BARF;
    // ---- ph6: buf1 kk0 g1 | stage b0.A0(tn0)
    rdA(LA1, 0, 1);
    if (st) SA(0, 0, tn0);
    BARF; MG(1); BARF;
    // ---- ph7: buf1 kk1 g0 | stage b0.A1(tn0)
    rdB(LB1, 1); rdA(LA1, 1, 0);
    if (st) SA(0, 1, tn0);
    BARF; MG(0); BARF;
    // ---- ph8: buf1 kk1 g1 | stage b1.B0(tn1) | vmcnt
    rdA(LA1, 1, 1);
    if (st) SB(1, 0, tn1);
    BARF; MG(1);
    if (st) {
      asm volatile("s_waitcnt vmcnt(2)" ::: "memory");
      BARF;
    }
  }

  int gmB = m0 + wr * 128;
  int gnB = n0 + wc * 64;
  if (EPI == 0) {
    int sec = n0 >> 9;                       // block-uniform (256-col tile)
    if (sec == 0) {
#pragma unroll
      for (int mf = 0; mf < 8; mf++) {
#pragma unroll
        for (int nf = 0; nf < 4; nf++) {
          int col = gnB + nf * 16 + lnlo;
          int hh = (col >> 6) & 7;
          int dd = col & 63;
#pragma unroll
          for (int r = 0; r < 4; r++) {
            int rowm = gmB + mf * 16 + lnhi * 4 + r;
            float val = acc[mf][nf][r];
            val = (val > 0.f) ? (val + 1.f) : __expf(val);  // elu+1
            int bidx = rowm >> 12, tok = rowm & 4095;
            qph[(((size_t)(bidx * 8 + hh) * 4096 + tok) << 6) + dd] = f2bf(val);
          }
        }
      }
    } else {
      u16* dstT = (sec == 1) ? kphT : vT;    // [bh][d=64][n=4096]
      bool isphi = (sec == 1);
#pragma unroll
      for (int mf = 0; mf < 8; mf++) {
        int rowm = gmB + mf * 16 + lnhi * 4;
        int bidx = rowm >> 12, tok = rowm & 4095;
#pragma unroll
        for (int nf = 0; nf < 4; nf++) {
          int col = gnB + nf * 16 + lnlo;
          int hh = (col >> 6) & 7;
          int dd = col & 63;
          s16x4 o4;
#pragma unroll
          for (int r = 0; r < 4; r++) {
            float val = acc[mf][nf][r];
            if (isphi) val = (val > 0.f) ? (val + 1.f) : __expf(val);
            o4[r] = (short)f2bf(val);
          }
          *(s16x4*)&dstT[((size_t)(bidx * 8 + hh) * 64 + dd) * 4096 + tok] = o4;
        }
      }
    }
  } else {
#pragma unroll
    for (int mf = 0; mf < 8; mf++) {
#pragma unroll
      for (int nf = 0; nf < 4; nf++) {
        int col = gnB + nf * 16 + lnlo;
        float bv = bias[col];
#pragma unroll
        for (int r = 0; r < 4; r++) {
          int rowm = gmB + mf * 16 + lnhi * 4 + r;
          out[(size_t)rowm * 512 + col] = acc[mf][nf][r] + bv;
        }
      }
    }
  }
}

// -------------------------------------------- KV partials via MFMA + Ksum
__global__ __launch_bounds__(256, 2) void k_kv(const u16* __restrict__ kphT,
                                               const u16* __restrict__ vT,
                                               float* __restrict__ kvpart,
                                               float* __restrict__ kspart) {
  __shared__ __align__(16) u16 lsK[64 * 256];   // 32 KB
  __shared__ __align__(16) u16 lsV[64 * 256];   // 32 KB
  __shared__ float red[4][64];
  int bx = blockIdx.x;
  int bh = bx >> 4, ck = bx & 15;
  int tid = threadIdx.x, w = tid >> 6, lane = tid & 63;
  int lnlo = lane & 15, lnhi = lane >> 4;
  size_t gbase = (size_t)bh * 64 * 4096 + ck * 256;

#pragma unroll
  for (int i = 0; i < 8; i++) {
    int c = tid + i * 256;
    int row = c >> 5, ch = c & 31;
    int gch = ch ^ (row & 31);
    gload16(kphT + gbase + (size_t)row * 4096 + gch * 8, &lsK[c * 8]);
  }
#pragma unroll
  for (int i = 0; i < 8; i++) {
    int c = tid + i * 256;
    int row = c >> 5, ch = c & 31;
    int gch = ch ^ (row & 31);
    gload16(vT + gbase + (size_t)row * 4096 + gch * 8, &lsV[c * 8]);
  }
  asm volatile("s_waitcnt vmcnt(0)" ::: "memory");
  __builtin_amdgcn_s_barrier();

  f32x4 acc[4] = {{0.f, 0.f, 0.f, 0.f}, {0.f, 0.f, 0.f, 0.f},
                  {0.f, 0.f, 0.f, 0.f}, {0.f, 0.f, 0.f, 0.f}};
  int rb = w * 16 + lnlo;
#pragma unroll
  for (int kk = 0; kk < 8; kk++) {
    s16x8 bfr = *(const s16x8*)&lsV[rb * 256 + ((kk * 4 + lnhi) ^ (rb & 31)) * 8];
#pragma unroll
    for (int mf = 0; mf < 4; mf++) {
      int ra = mf * 16 + lnlo;
      s16x8 af = *(const s16x8*)&lsK[ra * 256 + ((kk * 4 + lnhi) ^ (ra & 31)) * 8];
      acc[mf] = __builtin_amdgcn_mfma_f32_16x16x32_bf16(af, bfr, acc[mf], 0, 0, 0);
    }
  }

  {
    int d = tid & 63, q = tid >> 6;
    float s = 0.f;
#pragma unroll
    for (int j = 0; j < 8; j++) {
      s16x8 v8 = *(const s16x8*)&lsK[d * 256 + (q * 8 + j) * 8];
#pragma unroll
      for (int e = 0; e < 8; e++) s += bf2f((u16)v8[e]);
    }
    red[q][d] = s;
  }
  __syncthreads();

  size_t pb = (size_t)(bh * 16 + ck) * 4096;
#pragma unroll
  for (int mf = 0; mf < 4; mf++)
#pragma unroll
    for (int r = 0; r < 4; r++)
      kvpart[pb + (size_t)(mf * 16 + lnhi * 4 + r) * 64 + (w * 16 + lnlo)] = acc[mf][r];
  if (tid < 64)
    kspart[(size_t)(bh * 16 + ck) * 64 + tid] =
        red[0][tid] + red[1][tid] + red[2][tid] + red[3][tid];
}

// --------------------- reduce partials -> KVt[e][d] bf16 (pre-swizzled) + Ksum
__global__ __launch_bounds__(256) void k_kvred(const float* __restrict__ kvpart,
                                               const float* __restrict__ kspart,
                                               u16* __restrict__ kvt_sw,
                                               float* __restrict__ ksum) {
  int bh = blockIdx.x;
  int tid = threadIdx.x;
  int e = tid >> 2, d0 = (tid & 3) * 16;
  size_t pb = (size_t)bh * 16 * 4096;
#pragma unroll
  for (int dd = 0; dd < 16; dd++) {
    int d = d0 + dd;
    float s = 0.f;
#pragma unroll
    for (int c = 0; c < 16; c++) s += kvpart[pb + (size_t)c * 4096 + d * 64 + e];
    int chs = (d >> 3) ^ (e & 7);
    kvt_sw[((size_t)bh * 64 + e) * 64 + chs * 8 + (d & 7)] = f2bf(s);
  }
  if (tid < 64) {
    float s = 0.f;
#pragma unroll
    for (int c = 0; c < 16; c++) s += kspart[(size_t)bh * 1024 + c * 64 + tid];
    ksum[bh * 64 + tid] = s;
  }
}

// ------------------------- y[tok][h*64+e] = (q_phi @ KV) / (q_phi . Ksum + eps)
__global__ __launch_bounds__(256, 2) void k_attnout(const u16* __restrict__ qphi,
                                                    const u16* __restrict__ kvt_sw,
                                                    const float* __restrict__ ksum,
                                                    u16* __restrict__ y) {
  __shared__ __align__(16) u16 qa[256 * 64];
  __shared__ __align__(16) u16 bb[64 * 64];
  __shared__ float ksl[64];
  __shared__ float rdnl[256];
  int bx = blockIdx.x;
  int bh = bx >> 4, tch = bx & 15;
  int b = bh >> 3, hh = bh & 7;
  int tid = threadIdx.x, w = tid >> 6, lane = tid & 63;
  int lnlo = lane & 15, lnhi = lane >> 4;
  size_t qbase = ((size_t)bh * 4096 + tch * 256) * 64;

#pragma unroll
  for (int i = 0; i < 8; i++) {
    int c = i * 256 + tid;
    int row = c >> 3, ch = c & 7;
    int gcol = (ch ^ (row & 7)) << 3;
    gload16(qphi + qbase + (size_t)row * 64 + gcol, &qa[c * 8]);
  }
#pragma unroll
  for (int i = 0; i < 2; i++) {
    int c = i * 256 + tid;
    gload16(kvt_sw + (size_t)bh * 4096 + c * 8, &bb[c * 8]);
  }
  if (tid < 64) ksl[tid] = ksum[bh * 64 + tid];
  __syncthreads();

  {
    float den = 0.f;
#pragma unroll
    for (int ch = 0; ch < 8; ch++) {
      s16x8 v8 = *(const s16x8*)&qa[tid * 64 + ((ch ^ (tid & 7)) << 3)];
#pragma unroll
      for (int j = 0; j < 8; j++) den += bf2f((u16)v8[j]) * ksl[ch * 8 + j];
    }
    rdnl[tid] = 1.f / (den + 1e-6f);
  }
  __syncthreads();

  f32x4 acc[4][4] = {};
#pragma unroll
  for (int kk = 0; kk < 2; kk++) {
    s16x8 af[4], bfr[4];
#pragma unroll
    for (int f = 0; f < 4; f++) {
      int ra = w * 64 + f * 16 + lnlo;
      int ca = (kk * 4 + lnhi) ^ (ra & 7);
      af[f] = *(const s16x8*)&qa[ra * 64 + ca * 8];
      int rb = f * 16 + lnlo;
      int cb = (kk * 4 + lnhi) ^ (rb & 7);
      bfr[f] = *(const s16x8*)&bb[rb * 64 + cb * 8];
    }
#pragma unroll
    for (int mf = 0; mf < 4; mf++)
#pragma unroll
      for (int nf = 0; nf < 4; nf++)
        acc[mf][nf] = __builtin_amdgcn_mfma_f32_16x16x32_bf16(af[mf], bfr[nf], acc[mf][nf], 0, 0, 0);
  }

  size_t yrow0 = (size_t)b * 4096 + tch * 256;
#pragma unroll
  for (int mf = 0; mf < 4; mf++) {
#pragma unroll
    for (int nf = 0; nf < 4; nf++) {
      int e = nf * 16 + lnlo;
#pragma unroll
      for (int r = 0; r < 4; r++) {
        int tl = w * 64 + mf * 16 + lnhi * 4 + r;
        float val = acc[mf][nf][r] * rdnl[tl];
        y[(yrow0 + tl) * 512 + hh * 64 + e] = f2bf(val);
      }
    }
  }
}

// ------------------------------------------------------------------ launch
#define OFF_XB     ((size_t)0)             // 33,554,432  (also aliased as Y)
#define OFF_WQKVT  ((size_t)33554432)      //  1,572,864
#define OFF_WOUTT  ((size_t)35127296)      //    524,288
#define OFF_QPHI   ((size_t)35651584)      // 33,554,432
#define OFF_KPHI   ((size_t)69206016)      // 33,554,432  (kphiT [bh][64][4096])
#define OFF_VBUF   ((size_t)102760448)     // 33,554,432  (vT    [bh][64][4096])
#define OFF_KVPART ((size_t)136314880)     // 16,777,216
#define OFF_KSPART ((size_t)153092096)     //    262,144
#define OFF_KVT    ((size_t)153354240)     //    524,288
#define OFF_KSUM   ((size_t)153878528)     //     16,384

extern "C" void kernel_launch(void* const* d_in, const int* in_sizes, int n_in,
                              void* d_out, int out_size, void* d_ws, size_t ws_size,
                              hipStream_t stream) {
  const float* x    = (const float*)d_in[0];
  const float* Wqkv = (const float*)d_in[1];
  const float* Wout = (const float*)d_in[2];
  const float* bout = (const float*)d_in[3];
  float* out = (float*)d_out;
  char* ws = (char*)d_ws;

  u16* xb     = (u16*)(ws + OFF_XB);
  u16* y      = (u16*)(ws + OFF_XB);  // alias: xb dead after GEMM1
  u16* wqkvt  = (u16*)(ws + OFF_WQKVT);
  u16* woutt  = (u16*)(ws + OFF_WOUTT);
  u16* qphi   = (u16*)(ws + OFF_QPHI);
  u16* kphT   = (u16*)(ws + OFF_KPHI);
  u16* vT     = (u16*)(ws + OFF_VBUF);
  float* kvpart = (float*)(ws + OFF_KVPART);
  float* kspart = (float*)(ws + OFF_KSPART);
  u16* kvt_sw = (u16*)(ws + OFF_KVT);
  float* ksum = (float*)(ws + OFF_KSUM);

  k_prep<<<2304, 256, 0, stream>>>(x, xb, Wqkv, wqkvt, Wout, woutt);

  // qkv = xb @ Wqkv (+ phi epilogue; q direct, k/v transposed). 128x6 = 768
  k_gemm<0><<<768, 512, 0, stream>>>(xb, wqkvt, 6, qphi, kphT, vT, nullptr, nullptr);
  k_kv<<<64 * 16, 256, 0, stream>>>(kphT, vT, kvpart, kspart);
  k_kvred<<<64, 256, 0, stream>>>(kvpart, kspart, kvt_sw, ksum);
  k_attnout<<<64 * 16, 256, 0, stream>>>(qphi, kvt_sw, ksum, y);
  // out = y @ Wout + b. 128x2 = 256 blocks
  k_gemm<1><<<256, 512, 0, stream>>>(y, woutt, 2, nullptr, nullptr, nullptr, out, bout);
}

// Round 11
// 153.648 us; speedup vs baseline: 1.0462x; 1.0134x over previous
//
#include <hip/hip_runtime.h>
#include <stdint.h>

typedef float    f32x4 __attribute__((ext_vector_type(4)));
typedef short    s16x8 __attribute__((ext_vector_type(8)));
typedef short    s16x4 __attribute__((ext_vector_type(4)));
typedef unsigned short u16;
typedef uint32_t u32;

#define DEVINL __device__ __forceinline__

DEVINL float bf2f(u16 u) { union { u32 i; float f; } x; x.i = ((u32)u) << 16; return x.f; }
DEVINL u16 f2bf(float f) {
  union { float f; u32 i; } x; x.f = f;
  u32 i = x.i;
  return (u16)((i + 0x7FFFu + ((i >> 16) & 1u)) >> 16);  // RNE
}

DEVINL void gload16(const void* g, void* l) {
  __builtin_amdgcn_global_load_lds((const __attribute__((address_space(1))) void*)g,
                                   (__attribute__((address_space(3))) void*)l,
                                   16, 0, 0);
}

// --------------------------- prep: conv x->bf16 + both weight transposes
__global__ __launch_bounds__(256) void k_prep(const float* __restrict__ x,
                                              u16* __restrict__ xb,
                                              const float* __restrict__ Wqkv,
                                              u16* __restrict__ wqkvt,
                                              const float* __restrict__ Wout,
                                              u16* __restrict__ woutt) {
  __shared__ __align__(16) float t[64][65];
  int b = blockIdx.x;
  int tid = threadIdx.x;
  if (b < 2048) {
    const int n8 = 2097152;
    int stride = 2048 * 256;
    for (int i = b * 256 + tid; i < n8; i += stride) {
      const f32x4* p = (const f32x4*)(x + (size_t)i * 8);
      f32x4 a = p[0], c = p[1];
      s16x8 o;
      o[0] = (short)f2bf(a[0]); o[1] = (short)f2bf(a[1]);
      o[2] = (short)f2bf(a[2]); o[3] = (short)f2bf(a[3]);
      o[4] = (short)f2bf(c[0]); o[5] = (short)f2bf(c[1]);
      o[6] = (short)f2bf(c[2]); o[7] = (short)f2bf(c[3]);
      *(s16x8*)(xb + (size_t)i * 8) = o;
    }
    return;
  }
  const float* W; u16* Wt; int K, N, tb;
  if (b < 2048 + 192) { W = Wqkv; Wt = wqkvt; K = 512; N = 1536; tb = b - 2048; }
  else               { W = Wout; Wt = woutt; K = 512; N = 512;  tb = b - 2240; }
  int nb = N >> 6;
  int tn = tb % nb, tk = tb / nb;
  int n0 = tn << 6, k0 = tk << 6;
  int cr = tid >> 4, cc = (tid & 15) << 2;
#pragma unroll
  for (int i = 0; i < 4; i++) {
    int r = cr + (i << 4);
    f32x4 v = *(const f32x4*)(W + (size_t)(k0 + r) * N + n0 + cc);
    t[r][cc] = v[0]; t[r][cc + 1] = v[1]; t[r][cc + 2] = v[2]; t[r][cc + 3] = v[3];
  }
  __syncthreads();
#pragma unroll
  for (int i = 0; i < 4; i++) {
    int nn = cr + (i << 4);
    s16x4 o;
    o[0] = (short)f2bf(t[cc    ][nn]);
    o[1] = (short)f2bf(t[cc + 1][nn]);
    o[2] = (short)f2bf(t[cc + 2][nn]);
    o[3] = (short)f2bf(t[cc + 3][nn]);
    *(s16x4*)(Wt + (size_t)(n0 + nn) * K + k0 + cc) = o;
  }
}

// ------------------------------------------------------------------ GEMM1
// r4 K-loop (best measured). Epilogue: q direct (+phi) to qphi[bh][tok][d];
// k/v transposed s16x4 stores to kphiT/vT [bh][d][tok].
__global__ __launch_bounds__(512, 1) void k_gemm1(
    const u16* __restrict__ A, const u16* __restrict__ Bt,
    u16* __restrict__ qph, u16* __restrict__ kphT, u16* __restrict__ vT) {
  __shared__ __align__(16) u16 lsA[3][256 * 32];
  __shared__ __align__(16) u16 lsB[3][256 * 32];
  const int nbn = 6;
  int nwg = gridDim.x;
  int bx = blockIdx.x;
  int o = (bx & 7) * (nwg >> 3) + (bx >> 3);
  int bm = o / nbn, bn = o % nbn;
  int m0 = bm << 8, n0 = bn << 8;
  int tid = threadIdx.x;
  int w = tid >> 6, lane = tid & 63;
  int lnlo = lane & 15, lnhi = lane >> 4;
  int wr = w >> 2, wc = w & 3;

  const u16* gAp[2]; const u16* gBp[2]; int ldst[2];
#pragma unroll
  for (int i = 0; i < 2; i++) {
    int c = tid + i * 512;
    int row = c >> 2, ch = c & 3;
    int gch = ch ^ ((row >> 1) & 3);
    gAp[i] = A + (size_t)(m0 + row) * 512 + gch * 8;
    gBp[i] = Bt + (size_t)(n0 + row) * 512 + gch * 8;
    ldst[i] = c * 8;
  }
  int offA[8], offB[4];
#pragma unroll
  for (int f = 0; f < 8; f++) {
    int r = wr * 128 + f * 16 + lnlo;
    offA[f] = r * 32 + (lnhi ^ ((r >> 1) & 3)) * 8;
  }
#pragma unroll
  for (int f = 0; f < 4; f++) {
    int r = wc * 64 + f * 16 + lnlo;
    offB[f] = r * 32 + (lnhi ^ ((r >> 1) & 3)) * 8;
  }

  f32x4 acc[8][4] = {};

#pragma unroll
  for (int i = 0; i < 2; i++) gload16(gAp[i], &lsA[0][ldst[i]]);
#pragma unroll
  for (int i = 0; i < 2; i++) gload16(gBp[i], &lsB[0][ldst[i]]);
#pragma unroll
  for (int i = 0; i < 2; i++) gload16(gAp[i] + 32, &lsA[1][ldst[i]]);
#pragma unroll
  for (int i = 0; i < 2; i++) gload16(gBp[i] + 32, &lsB[1][ldst[i]]);
  asm volatile("s_waitcnt vmcnt(4)" ::: "memory");
  __builtin_amdgcn_s_barrier();

#pragma unroll
  for (int t = 0; t < 16; t++) {
    int buf = t % 3;
    const u16* La = &lsA[buf][0];
    const u16* Lb = &lsB[buf][0];
    int k2 = (t + 2) * 32;
    int b2 = (t + 2) % 3;

    s16x8 bf[4], af[4];
#pragma unroll
    for (int f = 0; f < 4; f++) bf[f] = *(const s16x8*)(Lb + offB[f]);
#pragma unroll
    for (int f = 0; f < 4; f++) af[f] = *(const s16x8*)(La + offA[f]);
    if (t < 14) {
#pragma unroll
      for (int i = 0; i < 2; i++) gload16(gAp[i] + k2, &lsA[b2][ldst[i]]);
    }
    __builtin_amdgcn_s_barrier();
    __builtin_amdgcn_s_setprio(1);
#pragma unroll
    for (int mf = 0; mf < 4; mf++)
#pragma unroll
      for (int nf = 0; nf < 4; nf++)
        acc[mf][nf] = __builtin_amdgcn_mfma_f32_16x16x32_bf16(af[mf], bf[nf], acc[mf][nf], 0, 0, 0);
    __builtin_amdgcn_s_setprio(0);
    __builtin_amdgcn_s_barrier();

    s16x8 af2[4];
#pragma unroll
    for (int f = 0; f < 4; f++) af2[f] = *(const s16x8*)(La + offA[4 + f]);
    if (t < 14) {
#pragma unroll
      for (int i = 0; i < 2; i++) gload16(gBp[i] + k2, &lsB[b2][ldst[i]]);
    }
    __builtin_amdgcn_s_barrier();
    __builtin_amdgcn_s_setprio(1);
#pragma unroll
    for (int mf = 0; mf < 4; mf++)
#pragma unroll
      for (int nf = 0; nf < 4; nf++)
        acc[4 + mf][nf] = __builtin_amdgcn_mfma_f32_16x16x32_bf16(af2[mf], bf[nf], acc[4 + mf][nf], 0, 0, 0);
    __builtin_amdgcn_s_setprio(0);
    if (t <= 13)      asm volatile("s_waitcnt vmcnt(4)" ::: "memory");
    else if (t == 14) asm volatile("s_waitcnt vmcnt(0)" ::: "memory");
    if (t < 15) __builtin_amdgcn_s_barrier();
  }

  int gmB = m0 + wr * 128;
  int gnB = n0 + wc * 64;
  int sec = n0 >> 9;
  if (sec == 0) {
#pragma unroll
    for (int mf = 0; mf < 8; mf++) {
#pragma unroll
      for (int nf = 0; nf < 4; nf++) {
        int col = gnB + nf * 16 + lnlo;
        int hh = (col >> 6) & 7;
        int dd = col & 63;
#pragma unroll
        for (int r = 0; r < 4; r++) {
          int rowm = gmB + mf * 16 + lnhi * 4 + r;
          float val = acc[mf][nf][r];
          val = (val > 0.f) ? (val + 1.f) : __expf(val);  // elu+1
          int bidx = rowm >> 12, tok = rowm & 4095;
          qph[(((size_t)(bidx * 8 + hh) * 4096 + tok) << 6) + dd] = f2bf(val);
        }
      }
    }
  } else {
    u16* dstT = (sec == 1) ? kphT : vT;    // [bh][d=64][n=4096]
    bool isphi = (sec == 1);
#pragma unroll
    for (int mf = 0; mf < 8; mf++) {
      int rowm = gmB + mf * 16 + lnhi * 4;
      int bidx = rowm >> 12, tok = rowm & 4095;
#pragma unroll
      for (int nf = 0; nf < 4; nf++) {
        int col = gnB + nf * 16 + lnlo;
        int hh = (col >> 6) & 7;
        int dd = col & 63;
        s16x4 o4;
#pragma unroll
        for (int r = 0; r < 4; r++) {
          float val = acc[mf][nf][r];
          if (isphi) val = (val > 0.f) ? (val + 1.f) : __expf(val);
          o4[r] = (short)f2bf(val);
        }
        *(s16x4*)&dstT[((size_t)(bidx * 8 + hh) * 64 + dd) * 4096 + tok] = o4;
      }
    }
  }
}

// -------------------------------------------- KV partials via MFMA + Ksum
__global__ __launch_bounds__(256, 2) void k_kv(const u16* __restrict__ kphT,
                                               const u16* __restrict__ vT,
                                               float* __restrict__ kvpart,
                                               float* __restrict__ kspart) {
  __shared__ __align__(16) u16 lsK[64 * 256];
  __shared__ __align__(16) u16 lsV[64 * 256];
  __shared__ float red[4][64];
  int bx = blockIdx.x;
  int bh = bx >> 4, ck = bx & 15;
  int tid = threadIdx.x, w = tid >> 6, lane = tid & 63;
  int lnlo = lane & 15, lnhi = lane >> 4;
  size_t gbase = (size_t)bh * 64 * 4096 + ck * 256;

#pragma unroll
  for (int i = 0; i < 8; i++) {
    int c = tid + i * 256;
    int row = c >> 5, ch = c & 31;
    int gch = ch ^ (row & 31);
    gload16(kphT + gbase + (size_t)row * 4096 + gch * 8, &lsK[c * 8]);
  }
#pragma unroll
  for (int i = 0; i < 8; i++) {
    int c = tid + i * 256;
    int row = c >> 5, ch = c & 31;
    int gch = ch ^ (row & 31);
    gload16(vT + gbase + (size_t)row * 4096 + gch * 8, &lsV[c * 8]);
  }
  asm volatile("s_waitcnt vmcnt(0)" ::: "memory");
  __builtin_amdgcn_s_barrier();

  f32x4 acc[4] = {{0.f, 0.f, 0.f, 0.f}, {0.f, 0.f, 0.f, 0.f},
                  {0.f, 0.f, 0.f, 0.f}, {0.f, 0.f, 0.f, 0.f}};
  int rb = w * 16 + lnlo;
#pragma unroll
  for (int kk = 0; kk < 8; kk++) {
    s16x8 bfr = *(const s16x8*)&lsV[rb * 256 + ((kk * 4 + lnhi) ^ (rb & 31)) * 8];
#pragma unroll
    for (int mf = 0; mf < 4; mf++) {
      int ra = mf * 16 + lnlo;
      s16x8 af = *(const s16x8*)&lsK[ra * 256 + ((kk * 4 + lnhi) ^ (ra & 31)) * 8];
      acc[mf] = __builtin_amdgcn_mfma_f32_16x16x32_bf16(af, bfr, acc[mf], 0, 0, 0);
    }
  }

  {
    int d = tid & 63, q = tid >> 6;
    float s = 0.f;
#pragma unroll
    for (int j = 0; j < 8; j++) {
      s16x8 v8 = *(const s16x8*)&lsK[d * 256 + (q * 8 + j) * 8];
#pragma unroll
      for (int e = 0; e < 8; e++) s += bf2f((u16)v8[e]);
    }
    red[q][d] = s;
  }
  __syncthreads();

  size_t pb = (size_t)(bh * 16 + ck) * 4096;
#pragma unroll
  for (int mf = 0; mf < 4; mf++)
#pragma unroll
    for (int r = 0; r < 4; r++)
      kvpart[pb + (size_t)(mf * 16 + lnhi * 4 + r) * 64 + (w * 16 + lnlo)] = acc[mf][r];
  if (tid < 64)
    kspart[(size_t)(bh * 16 + ck) * 64 + tid] =
        red[0][tid] + red[1][tid] + red[2][tid] + red[3][tid];
}

// ---------------------------------------------- W2 + per-head reciprocals
// blocks [0,64): bh -> W2T[b][n][h*64+d] = (reduce kvpart)[d][e] @ woutt rows
// blocks [64,576): (bh, tok-chunk) -> rdn[bh][tok] = 1/(qphi.ksum + eps)
__global__ __launch_bounds__(256) void k_w2(const float* __restrict__ kvpart,
                                            const float* __restrict__ kspart,
                                            const u16* __restrict__ woutt,
                                            const u16* __restrict__ qphi,
                                            u16* __restrict__ w2t,
                                            float* __restrict__ rdng) {
  __shared__ __align__(16) u16 kvls[64 * 64];
  __shared__ float ksumv[64];
  int blk = blockIdx.x, tid = threadIdx.x;
  if (blk < 64) {
    int bh = blk, b = bh >> 3, h = bh & 7;
    int w = tid >> 6, lane = tid & 63, lnlo = lane & 15, lnhi = lane >> 4;
    // reduce kvpart -> KV bf16 (swizzled ch^(d&7))
    int d = tid >> 2, e0 = (tid & 3) << 4;
    size_t pb = (size_t)bh * 16 * 4096;
    f32x4 s0 = {}, s1 = {}, s2 = {}, s3 = {};
    for (int c = 0; c < 16; c++) {
      const float* p = kvpart + pb + (size_t)c * 4096 + d * 64 + e0;
      s0 += *(const f32x4*)(p);
      s1 += *(const f32x4*)(p + 4);
      s2 += *(const f32x4*)(p + 8);
      s3 += *(const f32x4*)(p + 12);
    }
    s16x8 o0, o1;
#pragma unroll
    for (int j = 0; j < 4; j++) {
      o0[j] = (short)f2bf(s0[j]); o0[4 + j] = (short)f2bf(s1[j]);
      o1[j] = (short)f2bf(s2[j]); o1[4 + j] = (short)f2bf(s3[j]);
    }
    int ch0 = e0 >> 3;
    *(s16x8*)&kvls[d * 64 + (ch0 ^ (d & 7)) * 8] = o0;
    *(s16x8*)&kvls[d * 64 + ((ch0 + 1) ^ (d & 7)) * 8] = o1;
    __syncthreads();
    // C[d][n] = KV[d][e] @ woutt[n][h*64+e]^T ; wave w: n in [w*128, +128)
    f32x4 acc[4][8] = {};
#pragma unroll
    for (int kk = 0; kk < 2; kk++) {
      s16x8 af[4], bfr[8];
#pragma unroll
      for (int mf = 0; mf < 4; mf++) {
        int r = mf * 16 + lnlo;
        af[mf] = *(const s16x8*)&kvls[r * 64 + ((kk * 4 + lnhi) ^ (r & 7)) * 8];
      }
#pragma unroll
      for (int nf = 0; nf < 8; nf++) {
        int n = w * 128 + nf * 16 + lnlo;
        bfr[nf] = *(const s16x8*)&woutt[(size_t)n * 512 + h * 64 + (kk * 4 + lnhi) * 8];
      }
#pragma unroll
      for (int mf = 0; mf < 4; mf++)
#pragma unroll
        for (int nf = 0; nf < 8; nf++)
          acc[mf][nf] = __builtin_amdgcn_mfma_f32_16x16x32_bf16(af[mf], bfr[nf], acc[mf][nf], 0, 0, 0);
    }
#pragma unroll
    for (int mf = 0; mf < 4; mf++)
#pragma unroll
      for (int nf = 0; nf < 8; nf++) {
        int n = w * 128 + nf * 16 + lnlo;
        s16x4 o4;
#pragma unroll
        for (int r = 0; r < 4; r++) o4[r] = (short)f2bf(acc[mf][nf][r]);
        *(s16x4*)&w2t[(size_t)b * 262144 + (size_t)n * 512 + h * 64 + mf * 16 + lnhi * 4] = o4;
      }
  } else {
    int blk2 = blk - 64;
    int bh = blk2 >> 3, tch = blk2 & 7;
    if (tid < 64) {
      float s = 0.f;
#pragma unroll
      for (int c = 0; c < 16; c++) s += kspart[(size_t)bh * 1024 + c * 64 + tid];
      ksumv[tid] = s;
    }
    __syncthreads();
#pragma unroll
    for (int tt = 0; tt < 2; tt++) {
      int tok = tch * 512 + tid * 2 + tt;
      const u16* qp = qphi + ((size_t)bh * 4096 + tok) * 64;
      float den = 0.f;
#pragma unroll
      for (int cch = 0; cch < 8; cch++) {
        s16x8 v8 = *(const s16x8*)(qp + cch * 8);
        f32x4 k0 = *(const f32x4*)&ksumv[cch * 8];
        f32x4 k1 = *(const f32x4*)&ksumv[cch * 8 + 4];
#pragma unroll
        for (int j = 0; j < 4; j++) den += bf2f((u16)v8[j]) * k0[j];
#pragma unroll
        for (int j = 0; j < 4; j++) den += bf2f((u16)v8[4 + j]) * k1[j];
      }
      rdng[(size_t)bh * 4096 + tok] = 1.f / (den + 1e-6f);
    }
  }
}

// ----------------------------------------------------------------- k_out
// out[m][n] = (qphi_gather[m][k] * rdn) @ W2T[b][n][k] + bias[n].
// r4 K-loop; A reg-staged (gather across h-blocks, scaled by rdn during
// cvt->ds_write at end of phase b; loads issued phase a -> ~1-tile cover);
// B via gload_lds (3-buf). Compiler-inserted vmcnt at writeA drains older
// B-gloads (B(t+1) issued t-1 phase b is older than A(t+2) issued t phase a).
__global__ __launch_bounds__(512, 1) void k_out(
    const u16* __restrict__ qphi, const u16* __restrict__ w2t,
    const float* __restrict__ rdng, const float* __restrict__ bias,
    float* __restrict__ out) {
  __shared__ __align__(16) u16 lsA[3][256 * 32];
  __shared__ __align__(16) u16 lsB[3][256 * 32];
  int nwg = gridDim.x, bx = blockIdx.x;
  int o = (bx & 7) * (nwg >> 3) + (bx >> 3);
  int bm = o >> 1, bn = o & 1;
  int m0 = bm << 8, n0 = bn << 8;
  int b = m0 >> 12;
  int tid = threadIdx.x, w = tid >> 6, lane = tid & 63;
  int lnlo = lane & 15, lnhi = lane >> 4;
  int wr = w >> 2, wc = w & 3;

  int ldst[2];
  const u16* qb_[2]; const u16* gB_[2]; const float* rb_[2];
#pragma unroll
  for (int i = 0; i < 2; i++) {
    int c = tid + i * 512, row = c >> 2, ch = c & 3;
    int gch = ch ^ ((row >> 1) & 3);
    int tok = (m0 + row) & 4095;
    qb_[i] = qphi + ((size_t)(b * 8) * 4096 + tok) * 64 + gch * 8;
    rb_[i] = rdng + (size_t)(b * 8) * 4096 + tok;
    gB_[i] = w2t + (size_t)b * 262144 + (size_t)(n0 + row) * 512 + gch * 8;
    ldst[i] = c * 8;
  }
  int offA[8], offB[4];
#pragma unroll
  for (int f = 0; f < 8; f++) {
    int r = wr * 128 + f * 16 + lnlo;
    offA[f] = r * 32 + (lnhi ^ ((r >> 1) & 3)) * 8;
  }
#pragma unroll
  for (int f = 0; f < 4; f++) {
    int r = wc * 64 + f * 16 + lnlo;
    offB[f] = r * 32 + (lnhi ^ ((r >> 1) & 3)) * 8;
  }

  f32x4 acc[8][4] = {};
  s16x8 ar[2]; float rr[2];

  auto loadA = [&](int t) {
#pragma unroll
    for (int i = 0; i < 2; i++) {
      ar[i] = *(const s16x8*)(qb_[i] + (size_t)(t >> 1) * 262144 + (t & 1) * 32);
      rr[i] = rb_[i][(size_t)(t >> 1) * 4096];
    }
  };
  auto writeA = [&](int buf) {
#pragma unroll
    for (int i = 0; i < 2; i++) {
      s16x8 oo;
#pragma unroll
      for (int j = 0; j < 8; j++) oo[j] = (short)f2bf(bf2f((u16)ar[i][j]) * rr[i]);
      *(s16x8*)&lsA[buf][ldst[i]] = oo;
    }
  };
  auto stageB = [&](int t) {
    int buf = t % 3;
#pragma unroll
    for (int i = 0; i < 2; i++) gload16(gB_[i] + t * 32, &lsB[buf][ldst[i]]);
  };

  // prologue: A(0),A(1) synchronous reg->LDS; B(0),B(1) in flight
  loadA(0); writeA(0);
  loadA(1); writeA(1);
  stageB(0); stageB(1);
  asm volatile("s_waitcnt lgkmcnt(0)" ::: "memory");
  asm volatile("s_waitcnt vmcnt(2)" ::: "memory");   // B(0) landed; B(1) flying
  __builtin_amdgcn_s_barrier();

#pragma unroll
  for (int t = 0; t < 16; t++) {
    int buf = t % 3;
    const u16* La = &lsA[buf][0];
    const u16* Lb = &lsB[buf][0];

    s16x8 bf[4], af[4];
#pragma unroll
    for (int f = 0; f < 4; f++) bf[f] = *(const s16x8*)(Lb + offB[f]);
#pragma unroll
    for (int f = 0; f < 4; f++) af[f] = *(const s16x8*)(La + offA[f]);
    if (t < 14) loadA(t + 2);
    __builtin_amdgcn_s_barrier();
    __builtin_amdgcn_s_setprio(1);
#pragma unroll
    for (int mf = 0; mf < 4; mf++)
#pragma unroll
      for (int nf = 0; nf < 4; nf++)
        acc[mf][nf] = __builtin_amdgcn_mfma_f32_16x16x32_bf16(af[mf], bf[nf], acc[mf][nf], 0, 0, 0);
    __builtin_amdgcn_s_setprio(0);
    __builtin_amdgcn_s_barrier();

    s16x8 af2[4];
#pragma unroll
    for (int f = 0; f < 4; f++) af2[f] = *(const s16x8*)(La + offA[4 + f]);
    if (t < 14) stageB(t + 2);
    __builtin_amdgcn_s_barrier();
    __builtin_amdgcn_s_setprio(1);
#pragma unroll
    for (int mf = 0; mf < 4; mf++)
#pragma unroll
      for (int nf = 0; nf < 4; nf++)
        acc[4 + mf][nf] = __builtin_amdgcn_mfma_f32_16x16x32_bf16(af2[mf], bf[nf], acc[4 + mf][nf], 0, 0, 0);
    __builtin_amdgcn_s_setprio(0);
    if (t < 14) writeA((t + 2) % 3);     // compiler vmcnt drains B(t+1) too
    if (t == 14) asm volatile("s_waitcnt vmcnt(0)" ::: "memory");  // B(15)
    if (t < 15) {
      asm volatile("s_waitcnt lgkmcnt(0)" ::: "memory");
      __builtin_amdgcn_s_barrier();
    }
  }

  int gmB = m0 + wr * 128;
  int gnB = n0 + wc * 64;
#pragma unroll
  for (int mf = 0; mf < 8; mf++) {
#pragma unroll
    for (int nf = 0; nf < 4; nf++) {
      int col = gnB + nf * 16 + lnlo;
      float bv = bias[col];
#pragma unroll
      for (int r = 0; r < 4; r++) {
        int rowm = gmB + mf * 16 + lnhi * 4 + r;
        out[(size_t)rowm * 512 + col] = acc[mf][nf][r] + bv;
      }
    }
  }
}

// ------------------------------------------------------------------ launch
#define OFF_XB     ((size_t)0)             // 33.5MB xb; after GEMM1: w2t+rdn
#define OFF_W2T    ((size_t)0)             //  4,194,304 (alias xb)
#define OFF_RDN    ((size_t)4194304)       //  1,048,576 (alias xb)
#define OFF_WQKVT  ((size_t)33554432)      //  1,572,864
#define OFF_WOUTT  ((size_t)35127296)      //    524,288
#define OFF_QPHI   ((size_t)35651584)      // 33,554,432
#define OFF_KPHI   ((size_t)69206016)      // 33,554,432 (kphiT [bh][64][4096])
#define OFF_VBUF   ((size_t)102760448)     // 33,554,432 (vT    [bh][64][4096])
#define OFF_KVPART ((size_t)136314880)     // 16,777,216
#define OFF_KSPART ((size_t)153092096)     //    262,144

extern "C" void kernel_launch(void* const* d_in, const int* in_sizes, int n_in,
                              void* d_out, int out_size, void* d_ws, size_t ws_size,
                              hipStream_t stream) {
  const float* x    = (const float*)d_in[0];
  const float* Wqkv = (const float*)d_in[1];
  const float* Wout = (const float*)d_in[2];
  const float* bout = (const float*)d_in[3];
  float* out = (float*)d_out;
  char* ws = (char*)d_ws;

  u16* xb     = (u16*)(ws + OFF_XB);
  u16* w2t    = (u16*)(ws + OFF_W2T);   // alias: xb dead after GEMM1
  float* rdng = (float*)(ws + OFF_RDN); // alias: xb dead after GEMM1
  u16* wqkvt  = (u16*)(ws + OFF_WQKVT);
  u16* woutt  = (u16*)(ws + OFF_WOUTT);
  u16* qphi   = (u16*)(ws + OFF_QPHI);
  u16* kphT   = (u16*)(ws + OFF_KPHI);
  u16* vT     = (u16*)(ws + OFF_VBUF);
  float* kvpart = (float*)(ws + OFF_KVPART);
  float* kspart = (float*)(ws + OFF_KSPART);

  k_prep<<<2304, 256, 0, stream>>>(x, xb, Wqkv, wqkvt, Wout, woutt);
  k_gemm1<<<768, 512, 0, stream>>>(xb, wqkvt, qphi, kphT, vT);
  k_kv<<<1024, 256, 0, stream>>>(kphT, vT, kvpart, kspart);
  k_w2<<<576, 256, 0, stream>>>(kvpart, kspart, woutt, qphi, w2t, rdng);
  k_out<<<256, 512, 0, stream>>>(qphi, w2t, rdng, bout, out);
}